// Round 10
// baseline (1354.813 us; speedup 1.0000x reference)
//
#include <hip/hip_runtime.h>

#define BB 256
#define TT 512
#define II 64
#define DD 512
#define OO 128
#define LN_EPS 1e-5f
#define XS_STRIDE 68   // 64 + 4 pad
#define PF 4           // recur prefetch depth (steps ahead)

__device__ __forceinline__ float fast_tanh(float x) {
    // tanh(x) = 1 - 2/(exp(2x)+1); exact saturation at +/-inf
    float e = __expf(2.0f * x);
    return 1.0f - 2.0f / (e + 1.0f);
}

// ---------------------------------------------------------------------------
// Kernel 1: E[b][tau][d] = tanh(X[b, t0+tau, :] . W_in[d, :] + b_in[d])
// (unchanged — proven in round 6, not the bottleneck)
// ---------------------------------------------------------------------------
__global__ __launch_bounds__(256, 4)
void embed_kernel(const float* __restrict__ x,
                  const float* __restrict__ W_in,
                  const float* __restrict__ b_in,
                  float* __restrict__ E,
                  int t0, int CT)
{
    __shared__ float xs[II][XS_STRIDE];  // [i][n]
    __shared__ float ws[II][XS_STRIDE];  // [i][d]

    const int tiles_per_b = CT >> 6;
    const int bx   = blockIdx.x;
    const int b    = bx / tiles_per_b;
    const int tau0 = (bx - b * tiles_per_b) << 6;
    const int d0   = blockIdx.y << 6;
    const int tid  = threadIdx.x;

    {
        const int r0 = tid >> 4;
        const int c4 = tid & 15;
        #pragma unroll
        for (int rr = 0; rr < 4; ++rr) {
            const int row = r0 + (rr << 4);
            const float4 xv = *(const float4*)(x + ((size_t)(b * TT + t0 + tau0 + row)) * II + c4 * 4);
            const float4 wv = *(const float4*)(W_in + ((size_t)(d0 + row)) * II + c4 * 4);
            xs[c4 * 4 + 0][row] = xv.x; xs[c4 * 4 + 1][row] = xv.y;
            xs[c4 * 4 + 2][row] = xv.z; xs[c4 * 4 + 3][row] = xv.w;
            ws[c4 * 4 + 0][row] = wv.x; ws[c4 * 4 + 1][row] = wv.y;
            ws[c4 * 4 + 2][row] = wv.z; ws[c4 * 4 + 3][row] = wv.w;
        }
    }
    __syncthreads();

    const int tn = tid & 15;
    const int td = tid >> 4;

    float acc[4][4];
    #pragma unroll
    for (int j = 0; j < 4; ++j)
        #pragma unroll
        for (int k = 0; k < 4; ++k) acc[j][k] = 0.0f;

    #pragma unroll 8
    for (int i = 0; i < II; ++i) {
        const float4 xv = *(const float4*)&xs[i][tn * 4];
        const float4 wv = *(const float4*)&ws[i][td * 4];
        acc[0][0] = fmaf(xv.x, wv.x, acc[0][0]);
        acc[0][1] = fmaf(xv.x, wv.y, acc[0][1]);
        acc[0][2] = fmaf(xv.x, wv.z, acc[0][2]);
        acc[0][3] = fmaf(xv.x, wv.w, acc[0][3]);
        acc[1][0] = fmaf(xv.y, wv.x, acc[1][0]);
        acc[1][1] = fmaf(xv.y, wv.y, acc[1][1]);
        acc[1][2] = fmaf(xv.y, wv.z, acc[1][2]);
        acc[1][3] = fmaf(xv.y, wv.w, acc[1][3]);
        acc[2][0] = fmaf(xv.z, wv.x, acc[2][0]);
        acc[2][1] = fmaf(xv.z, wv.y, acc[2][1]);
        acc[2][2] = fmaf(xv.z, wv.z, acc[2][2]);
        acc[2][3] = fmaf(xv.z, wv.w, acc[2][3]);
        acc[3][0] = fmaf(xv.w, wv.x, acc[3][0]);
        acc[3][1] = fmaf(xv.w, wv.y, acc[3][1]);
        acc[3][2] = fmaf(xv.w, wv.z, acc[3][2]);
        acc[3][3] = fmaf(xv.w, wv.w, acc[3][3]);
    }

    const int dg = d0 + td * 4;
    const float4 bv = *(const float4*)(b_in + dg);
    #pragma unroll
    for (int j = 0; j < 4; ++j) {
        const int n = tau0 + tn * 4 + j;
        float4 ev;
        ev.x = fast_tanh(acc[j][0] + bv.x);
        ev.y = fast_tanh(acc[j][1] + bv.y);
        ev.z = fast_tanh(acc[j][2] + bv.z);
        ev.w = fast_tanh(acc[j][3] + bv.w);
        *(float4*)(E + ((size_t)(b * CT + n)) * DD + dg) = ev;
    }
}

// ---------------------------------------------------------------------------
// Kernel 2: recurrence + LN, ONE WAVE per row, BIT-IDENTICAL to round 6.
// Evidence (rounds 2,7,8,9 all ~0.46 vs passes all exactly 0.015625; rounds
// 7 & 9 bit-identical failures with DIFFERENT trees): the model is a
// contracting fixed-point iteration with knife-edge bifurcations — rounding
// differences are forgotten EXCEPT at branch points, where any deviation from
// the reference trajectory lands on a different fixed point (~0.46). So we
// reproduce round 6's arithmetic exactly and change only execution placement:
//   - lane l owns the 8 elements d = 64j + l (j=0..7);
//   - butterfly over lanes for each j == round 6's wave-j butterfly
//     (same elements, same descending m=32..1 xor tree -> bit-identical,
//     and butterfly results are bit-identical in every lane);
//   - serial ascending combine over j == round 6's `sum += red[wv]` loop;
//   - tanh / mu / var / rstd / h expressions copied verbatim.
// No LDS, no barriers; 16 independent butterfly streams pipeline.
// ---------------------------------------------------------------------------
__global__ __launch_bounds__(64, 1)
void recur_kernel(const float* __restrict__ E,
                  const float* __restrict__ gamma,
                  const float* __restrict__ beta,
                  const float* __restrict__ cs,
                  float* __restrict__ s_state,
                  float* __restrict__ h_state,
                  int CT, int is_first)
{
    const int b = blockIdx.x;
    const int l = threadIdx.x;

    float g[8], bt[8], s[8], h[8];
    #pragma unroll
    for (int j = 0; j < 8; ++j) {
        g[j]  = gamma[64 * j + l];
        bt[j] = beta[64 * j + l];
    }
    const float scale = 1.0f / (1.0f + __expf(-cs[0]));

    if (is_first) {
        #pragma unroll
        for (int j = 0; j < 8; ++j) { s[j] = 0.0f; h[j] = 0.0f; }
    } else {
        #pragma unroll
        for (int j = 0; j < 8; ++j) {
            s[j] = s_state[(size_t)b * DD + 64 * j + l];
            h[j] = h_state[(size_t)b * DD + 64 * j + l];
        }
    }

    const float* Eb = E + (size_t)b * CT * DD;

    float pf[PF][8];
    #pragma unroll
    for (int k = 0; k < PF; ++k)
        #pragma unroll
        for (int j = 0; j < 8; ++j)
            pf[k][j] = Eb[(size_t)k * DD + 64 * j + l];

    #pragma unroll 1
    for (int tau = 0; tau < CT; ++tau) {
        const int k = tau & (PF - 1);
        float e[8];
        #pragma unroll
        for (int j = 0; j < 8; ++j) e[j] = pf[k][j];
        const int tnx = tau + PF;
        if (tnx < CT) {
            #pragma unroll
            for (int j = 0; j < 8; ++j)
                pf[k][j] = Eb[(size_t)tnx * DD + 64 * j + l];
        }

        // s = tanh(e + scale*s_prev + h_prev)   (round-6 expression, verbatim)
        #pragma unroll
        for (int j = 0; j < 8; ++j)
            s[j] = fast_tanh(e[j] + scale * s[j] + h[j]);

        // round-6 butterfly per 64-block, 8 blocks in parallel streams
        float r0[8], r1[8];
        #pragma unroll
        for (int j = 0; j < 8; ++j) { r0[j] = s[j]; r1[j] = s[j] * s[j]; }
        #pragma unroll
        for (int m = 32; m >= 1; m >>= 1) {
            #pragma unroll
            for (int j = 0; j < 8; ++j) {
                r0[j] += __shfl_xor(r0[j], m, 64);
                r1[j] += __shfl_xor(r1[j], m, 64);
            }
        }

        // serial ascending combine (== round 6's `for wv: sum += red[wv]`)
        float sum = 0.f, sumsq = 0.f;
        #pragma unroll
        for (int j = 0; j < 8; ++j) {
            sum   += r0[j];
            sumsq += r1[j];
        }

        const float mu   = sum * (1.0f / DD);
        const float var  = sumsq * (1.0f / DD) - mu * mu;
        const float rstd = rsqrtf(var + LN_EPS);

        #pragma unroll
        for (int j = 0; j < 8; ++j)
            h[j] = (s[j] - mu) * rstd * g[j] + bt[j];
    }

    #pragma unroll
    for (int j = 0; j < 8; ++j) {
        s_state[(size_t)b * DD + 64 * j + l] = s[j];
        h_state[(size_t)b * DD + 64 * j + l] = h[j];
    }
}

// ---------------------------------------------------------------------------
// Kernel 3: logits[b, o] = h_final . W_out[o, :] + b_out[o]  (proven)
// ---------------------------------------------------------------------------
__global__ __launch_bounds__(512, 2)
void out_kernel(const float* __restrict__ h_state,
                const float* __restrict__ W_out,
                const float* __restrict__ b_out,
                float* __restrict__ out)
{
    const int b    = blockIdx.x;
    const int tid  = threadIdx.x;
    const int wave = tid >> 6;
    const int lane = tid & 63;

    __shared__ float h_lds[DD];
    h_lds[tid] = h_state[(size_t)b * DD + tid];
    __syncthreads();

    const int dbase = lane * 8;
    float hreg[8];
    #pragma unroll
    for (int k = 0; k < 8; ++k) hreg[k] = h_lds[dbase + k];

    for (int oo = 0; oo < 16; ++oo) {
        const int o = wave * 16 + oo;
        const float* wo = W_out + (size_t)o * DD + dbase;
        float pacc = 0.f;
        #pragma unroll
        for (int k = 0; k < 8; ++k) pacc = fmaf(wo[k], hreg[k], pacc);
        #pragma unroll
        for (int m = 32; m >= 1; m >>= 1) pacc += __shfl_xor(pacc, m, 64);
        if (lane == 0) out[(size_t)b * OO + o] = pacc + b_out[o];
    }
}

extern "C" void kernel_launch(void* const* d_in, const int* in_sizes, int n_in,
                              void* d_out, int out_size, void* d_ws, size_t ws_size,
                              hipStream_t stream) {
    const float* x      = (const float*)d_in[0];
    const float* W_in   = (const float*)d_in[1];
    const float* b_in   = (const float*)d_in[2];
    const float* gamma  = (const float*)d_in[3];
    const float* beta   = (const float*)d_in[4];
    const float* W_out  = (const float*)d_in[5];
    const float* b_out  = (const float*)d_in[6];
    const float* cs     = (const float*)d_in[7];
    float* out = (float*)d_out;

    // Workspace: [ E_chunk (BB*CT*DD fp32) | s_state (BB*DD) | h_state (BB*DD) ]
    const size_t state_bytes = (size_t)BB * DD * sizeof(float);
    int CT = TT;
    while (CT > 64 &&
           (size_t)BB * CT * DD * sizeof(float) + 2 * state_bytes > ws_size) {
        CT >>= 1;
    }
    float* E       = (float*)d_ws;
    float* s_state = (float*)((char*)d_ws + (size_t)BB * CT * DD * sizeof(float));
    float* h_state = s_state + (size_t)BB * DD;

    const int nchunks = TT / CT;
    for (int c = 0; c < nchunks; ++c) {
        dim3 g1(BB * (CT >> 6), DD >> 6);
        embed_kernel<<<g1, 256, 0, stream>>>(x, W_in, b_in, E, c * CT, CT);
        recur_kernel<<<BB, 64, 0, stream>>>(E, gamma, beta, cs,
                                            s_state, h_state, CT,
                                            (c == 0) ? 1 : 0);
    }
    out_kernel<<<BB, 512, 0, stream>>>(h_state, W_out, b_out, out);
}